// Round 1
// baseline (269.167 us; speedup 1.0000x reference)
//
#include <hip/hip_runtime.h>
#include <math.h>

// GEBLNet: two complex bilinear layers + trace-relu + trace-norm + dense head.
// One block (256 threads) per point p in [0, 8192). The 4 "u" channels are
// pass-through and never affect the output -> skipped entirely.
//
// Layer algebra (per point):
//   Wext[v] (V channels of 3x3 complex): [cin originals | cin conj-transposes | I]
//   B[u][v] = sum_w weight[u,v,w] * Wext[w]          (complex scalar * matrix)
//   H[u]    = sum_v Wext[v] @ B[u][v]                (complex 3x3 matmul)
//   == sum_{v,w} weight[u,v,w] * (Wext[v] @ Wext[w])   (reference's ww+contract)
// gerelu: s[u] = relu(Re tr H[u]);  trnorm: norm = max(mean_u s[u]*|tr H[u]|, 1e-3)
//   next-layer input channel = (s[u]/norm) * H[u]

#define THRESH 0.001f

__global__ __launch_bounds__(256) void geblnet_kernel(
    const float* __restrict__ x,      // (2,4096,10,3,3,2)
    const float* __restrict__ w1,     // (12,13,13,2)
    const float* __restrict__ w2,     // (12,25,25,2)
    const float* __restrict__ dw,     // (24,)
    const float* __restrict__ db,     // (1,)
    float* __restrict__ out)          // (8192,)
{
    const int p = blockIdx.x;
    const int t = threadIdx.x;

    __shared__ float Wext[25][9][2];      // 450 f
    __shared__ float Bm[12][25][9][2];    // 5400 f (21.6 KB)
    __shared__ float H[12][9][2];         // 216 f
    __shared__ float g[12];               // relu(tr_re) per channel
    __shared__ float tra[12];             // s*|tr|
    __shared__ float trre[12], trim[12];  // raw traces (layer-2 head)
    __shared__ float red[12];
    __shared__ float norm_s;

    const float* xp = x + (size_t)p * 180;   // 10 ch * 9 * 2

    // ======== Layer 1 (cin=6, V=13) ========
    if (t < 13 * 9) {
        int v = t / 9, ik = t % 9, i = ik / 3, j = ik % 3;
        float re, im;
        if (v < 6) {
            const float* s = xp + (4 + v) * 18 + ik * 2;
            re = s[0]; im = s[1];
        } else if (v < 12) {
            const float* s = xp + (4 + (v - 6)) * 18 + (j * 3 + i) * 2;
            re = s[0]; im = -s[1];
        } else {
            re = (i == j) ? 1.f : 0.f; im = 0.f;
        }
        Wext[v][ik][0] = re; Wext[v][ik][1] = im;
    }
    __syncthreads();

    // B[u][v][jk] = sum_w w1[u,v,w] * Wext[w][jk]
    for (int e = t; e < 12 * 13 * 9; e += 256) {
        int u = e / (13 * 9);
        int r = e % (13 * 9);
        int v = r / 9, jk = r % 9;
        const float* wp = w1 + ((u * 13 + v) * 13) * 2;
        float br = 0.f, bi = 0.f;
        #pragma unroll
        for (int w = 0; w < 13; ++w) {
            float wr = wp[w * 2], wi = wp[w * 2 + 1];
            float ar = Wext[w][jk][0], ai = Wext[w][jk][1];
            br += wr * ar - wi * ai;
            bi += wr * ai + wi * ar;
        }
        Bm[u][v][jk][0] = br; Bm[u][v][jk][1] = bi;
    }
    __syncthreads();

    // H[u] = sum_v Wext[v] @ B[u][v]
    if (t < 108) {
        int u = t / 9, ik = t % 9, i = ik / 3, k = ik % 3;
        float hr = 0.f, hi = 0.f;
        #pragma unroll 1
        for (int v = 0; v < 13; ++v) {
            #pragma unroll
            for (int j = 0; j < 3; ++j) {
                float ar = Wext[v][i * 3 + j][0], ai = Wext[v][i * 3 + j][1];
                float br = Bm[u][v][j * 3 + k][0], bi = Bm[u][v][j * 3 + k][1];
                hr += ar * br - ai * bi;
                hi += ar * bi + ai * br;
            }
        }
        H[u][ik][0] = hr; H[u][ik][1] = hi;
    }
    __syncthreads();

    // gerelu + trnorm scale factors
    if (t < 12) {
        float rr = H[t][0][0] + H[t][4][0] + H[t][8][0];
        float ri = H[t][0][1] + H[t][4][1] + H[t][8][1];
        float s = rr > 0.f ? rr : 0.f;
        g[t] = s;
        tra[t] = s * sqrtf(rr * rr + ri * ri);
    }
    __syncthreads();
    if (t == 0) {
        float m = 0.f;
        #pragma unroll
        for (int u = 0; u < 12; ++u) m += tra[u];
        norm_s = fmaxf(m * (1.f / 12.f), THRESH);
    }
    __syncthreads();
    const float inv1 = 1.f / norm_s;

    // ======== Layer 2 (cin=12, V=25) ========
    if (t < 25 * 9) {
        int v = t / 9, ik = t % 9, i = ik / 3, j = ik % 3;
        float re, im;
        if (v < 12) {
            float s = g[v] * inv1;
            re = s * H[v][ik][0]; im = s * H[v][ik][1];
        } else if (v < 24) {
            int sv = v - 12;
            float s = g[sv] * inv1;
            re = s * H[sv][j * 3 + i][0]; im = -s * H[sv][j * 3 + i][1];
        } else {
            re = (i == j) ? 1.f : 0.f; im = 0.f;
        }
        Wext[v][ik][0] = re; Wext[v][ik][1] = im;
    }
    __syncthreads();

    // B[u][v][jk] = sum_w w2[u,v,w] * Wext[w][jk]   (dominant phase)
    for (int e = t; e < 12 * 25 * 9; e += 256) {
        int u = e / (25 * 9);
        int r = e % (25 * 9);
        int v = r / 9, jk = r % 9;
        const float* wp = w2 + ((u * 25 + v) * 25) * 2;
        float br = 0.f, bi = 0.f;
        #pragma unroll
        for (int w = 0; w < 25; ++w) {
            float wr = wp[w * 2], wi = wp[w * 2 + 1];
            float ar = Wext[w][jk][0], ai = Wext[w][jk][1];
            br += wr * ar - wi * ai;
            bi += wr * ai + wi * ar;
        }
        Bm[u][v][jk][0] = br; Bm[u][v][jk][1] = bi;
    }
    __syncthreads();

    if (t < 108) {
        int u = t / 9, ik = t % 9, i = ik / 3, k = ik % 3;
        float hr = 0.f, hi = 0.f;
        #pragma unroll 1
        for (int v = 0; v < 25; ++v) {
            #pragma unroll
            for (int j = 0; j < 3; ++j) {
                float ar = Wext[v][i * 3 + j][0], ai = Wext[v][i * 3 + j][1];
                float br = Bm[u][v][j * 3 + k][0], bi = Bm[u][v][j * 3 + k][1];
                hr += ar * br - ai * bi;
                hi += ar * bi + ai * br;
            }
        }
        H[u][ik][0] = hr; H[u][ik][1] = hi;
    }
    __syncthreads();

    // final gerelu + trnorm + trace head
    if (t < 12) {
        float rr = H[t][0][0] + H[t][4][0] + H[t][8][0];
        float ri = H[t][0][1] + H[t][4][1] + H[t][8][1];
        float s = rr > 0.f ? rr : 0.f;
        g[t] = s;
        tra[t] = s * sqrtf(rr * rr + ri * ri);
        trre[t] = rr; trim[t] = ri;
    }
    __syncthreads();
    if (t == 0) {
        float m = 0.f;
        #pragma unroll
        for (int u = 0; u < 12; ++u) m += tra[u];
        norm_s = fmaxf(m * (1.f / 12.f), THRESH);
    }
    __syncthreads();
    if (t < 12) {
        float sc = g[t] / norm_s;                 // channel scale after relu+norm
        float fr = (1.f / 3.f) * sc * trre[t];    // tr = (1/3) * trace
        float fi = (1.f / 3.f) * sc * trim[t];
        red[t] = fr * dw[2 * t] + fi * dw[2 * t + 1];
    }
    __syncthreads();
    if (t == 0) {
        float acc = db[0];
        #pragma unroll
        for (int u = 0; u < 12; ++u) acc += red[u];
        out[p] = acc;
    }
}

extern "C" void kernel_launch(void* const* d_in, const int* in_sizes, int n_in,
                              void* d_out, int out_size, void* d_ws, size_t ws_size,
                              hipStream_t stream) {
    const float* x  = (const float*)d_in[0];
    const float* w1 = (const float*)d_in[1];
    const float* w2 = (const float*)d_in[2];
    const float* dw = (const float*)d_in[3];
    const float* db = (const float*)d_in[4];
    float* outp = (float*)d_out;
    const int npts = out_size;  // 2 * 4096 = 8192
    geblnet_kernel<<<npts, 256, 0, stream>>>(x, w1, w2, dw, db, outp);
}